// Round 1
// baseline (842.370 us; speedup 1.0000x reference)
//
#include <hip/hip_runtime.h>
#include <math.h>

// Problem constants
constexpr int D_MODEL_C = 1024;
constexpr int D_HEAD_C  = 64;
constexpr int S_C       = 4096;
constexpr int B_C       = 4;

// ---------------- QKV projection ----------------
// C[16384,192] = x[16384,1024] @ [Wq|Wk|Wv], + bias.
// Block: 192 threads = 3 waves, wave p handles projection p (uniform W ptr per wave).
// 8 rows per block; x tile staged TRANSPOSED in LDS so the K-loop reads the
// 8-row slice as two ds_read_b128 broadcasts (same addr across lanes -> free).
constexpr int PROWS    = 8;
constexpr int PTHREADS = 192;

__global__ __launch_bounds__(PTHREADS) void qkv_proj_kernel(
    const float* __restrict__ x,
    const float* __restrict__ Wq, const float* __restrict__ bq,
    const float* __restrict__ Wk, const float* __restrict__ bk,
    const float* __restrict__ Wv, const float* __restrict__ bv,
    float* __restrict__ Q, float* __restrict__ K, float* __restrict__ V)
{
    __shared__ float xs[D_MODEL_C][PROWS];  // transposed x tile, 32 KiB
    const int tid = threadIdx.x;
    const long r0 = (long)blockIdx.x * PROWS;

    // Stage: chunk c -> (r = c&7, k4 = c>>3); global float4 load coalesced over k.
    for (int c = tid; c < PROWS * (D_MODEL_C / 4); c += PTHREADS) {
        const int r  = c & (PROWS - 1);
        const int k4 = c >> 3;
        const float4 v = *reinterpret_cast<const float4*>(x + (r0 + r) * D_MODEL_C + k4 * 4);
        xs[k4 * 4 + 0][r] = v.x;
        xs[k4 * 4 + 1][r] = v.y;
        xs[k4 * 4 + 2][r] = v.z;
        xs[k4 * 4 + 3][r] = v.w;
    }
    __syncthreads();

    const int h = tid & 63;
    const int p = tid >> 6;  // 0=Q wave, 1=K wave, 2=V wave
    const float* __restrict__ W    = (p == 0) ? Wq : (p == 1) ? Wk : Wv;
    const float* __restrict__ bias = (p == 0) ? bq : (p == 1) ? bk : bv;
    float* __restrict__ O          = (p == 0) ? Q  : (p == 1) ? K  : V;

    float acc[PROWS];
#pragma unroll
    for (int r = 0; r < PROWS; ++r) acc[r] = 0.0f;

#pragma unroll 4
    for (int k = 0; k < D_MODEL_C; ++k) {
        const float w = W[k * D_HEAD_C + h];  // coalesced 256B per wave, L2-resident
        const float4 a0 = *reinterpret_cast<const float4*>(&xs[k][0]);
        const float4 a1 = *reinterpret_cast<const float4*>(&xs[k][4]);
        acc[0] = fmaf(a0.x, w, acc[0]);
        acc[1] = fmaf(a0.y, w, acc[1]);
        acc[2] = fmaf(a0.z, w, acc[2]);
        acc[3] = fmaf(a0.w, w, acc[3]);
        acc[4] = fmaf(a1.x, w, acc[4]);
        acc[5] = fmaf(a1.y, w, acc[5]);
        acc[6] = fmaf(a1.z, w, acc[6]);
        acc[7] = fmaf(a1.w, w, acc[7]);
    }
    const float bb = bias[h];
#pragma unroll
    for (int r = 0; r < PROWS; ++r)
        O[(r0 + r) * D_HEAD_C + h] = acc[r] + bb;  // coalesced over h
}

// ---------------- Causal flash attention ----------------
// Block: 128 threads, 32 q-rows (4 lanes per row, 16 d-elems each).
// K/V tiles of 64 staged in LDS; two passes per tile (s[64] in regs) so the
// online-softmax rescale of o[] happens once per tile, not per k.
// q-tiles processed in REVERSED blockIdx order: heavy diagonal blocks first.
constexpr int QT       = 32;
constexpr int KT       = 64;
constexpr int ATHREADS = 128;

__global__ __launch_bounds__(ATHREADS) void attn_kernel(
    const float* __restrict__ Q, const float* __restrict__ K,
    const float* __restrict__ V, float* __restrict__ out)
{
    __shared__ float Ks[KT][D_HEAD_C];  // 16 KiB
    __shared__ float Vs[KT][D_HEAD_C];  // 16 KiB

    const int tid  = threadIdx.x;
    const int rl   = tid >> 2;                       // local q-row 0..31
    const int part = tid & 3;                        // d-slice 0..3 (16 elems)
    const int qt   = (int)gridDim.x - 1 - (int)blockIdx.x;  // reversed for balance
    const int b    = blockIdx.y;
    const int grow = qt * QT + rl;                   // global q-row
    const long base = (long)b * S_C * D_HEAD_C;

    float q[16], o[16];
#pragma unroll
    for (int i = 0; i < 4; ++i) {
        const float4 qv = *reinterpret_cast<const float4*>(
            Q + base + (long)grow * D_HEAD_C + part * 16 + i * 4);
        q[i * 4 + 0] = qv.x * 0.125f;  // fold softmax scale 1/sqrt(64) into q
        q[i * 4 + 1] = qv.y * 0.125f;
        q[i * 4 + 2] = qv.z * 0.125f;
        q[i * 4 + 3] = qv.w * 0.125f;
        o[i * 4 + 0] = 0.0f; o[i * 4 + 1] = 0.0f;
        o[i * 4 + 2] = 0.0f; o[i * 4 + 3] = 0.0f;
    }
    float m = -1e30f, l = 0.0f;

    const int ntiles = (qt * QT + QT - 1) / KT + 1;
    for (int kt = 0; kt < ntiles; ++kt) {
        // Stage K/V tile (coalesced float4, linear LDS layout)
        for (int c = tid; c < KT * (D_HEAD_C / 4); c += ATHREADS) {
            const int row = c >> 4;
            const int col = (c & 15) * 4;
            const long g = base + (long)(kt * KT + row) * D_HEAD_C + col;
            *reinterpret_cast<float4*>(&Ks[row][col]) = *reinterpret_cast<const float4*>(K + g);
            *reinterpret_cast<float4*>(&Vs[row][col]) = *reinterpret_cast<const float4*>(V + g);
        }
        __syncthreads();

        // Pass 1: scores for this tile into registers
        float s[KT];
        float tm = -1e30f;
        const int kbase = kt * KT;
#pragma unroll
        for (int k = 0; k < KT; ++k) {
            const float4 k0 = *reinterpret_cast<const float4*>(&Ks[k][part * 16 + 0]);
            const float4 k1 = *reinterpret_cast<const float4*>(&Ks[k][part * 16 + 4]);
            const float4 k2 = *reinterpret_cast<const float4*>(&Ks[k][part * 16 + 8]);
            const float4 k3 = *reinterpret_cast<const float4*>(&Ks[k][part * 16 + 12]);
            float sv = 0.0f;
            sv = fmaf(q[0],  k0.x, sv); sv = fmaf(q[1],  k0.y, sv);
            sv = fmaf(q[2],  k0.z, sv); sv = fmaf(q[3],  k0.w, sv);
            sv = fmaf(q[4],  k1.x, sv); sv = fmaf(q[5],  k1.y, sv);
            sv = fmaf(q[6],  k1.z, sv); sv = fmaf(q[7],  k1.w, sv);
            sv = fmaf(q[8],  k2.x, sv); sv = fmaf(q[9],  k2.y, sv);
            sv = fmaf(q[10], k2.z, sv); sv = fmaf(q[11], k2.w, sv);
            sv = fmaf(q[12], k3.x, sv); sv = fmaf(q[13], k3.y, sv);
            sv = fmaf(q[14], k3.z, sv); sv = fmaf(q[15], k3.w, sv);
            sv += __shfl_xor(sv, 1);   // reduce across the 4 d-slices
            sv += __shfl_xor(sv, 2);
            if (kbase + k > grow) sv = -1e30f;  // causal mask
            s[k] = sv;
            tm = fmaxf(tm, sv);
        }

        // Online softmax update, one rescale per tile
        const float mn   = fmaxf(m, tm);
        const float corr = __expf(m - mn);
        l *= corr;
#pragma unroll
        for (int i = 0; i < 16; ++i) o[i] *= corr;

        // Pass 2: o += exp(s-mn) * V
#pragma unroll
        for (int k = 0; k < KT; ++k) {
            const float p = __expf(s[k] - mn);
            l += p;
            const float4 v0 = *reinterpret_cast<const float4*>(&Vs[k][part * 16 + 0]);
            const float4 v1 = *reinterpret_cast<const float4*>(&Vs[k][part * 16 + 4]);
            const float4 v2 = *reinterpret_cast<const float4*>(&Vs[k][part * 16 + 8]);
            const float4 v3 = *reinterpret_cast<const float4*>(&Vs[k][part * 16 + 12]);
            o[0]  = fmaf(p, v0.x, o[0]);  o[1]  = fmaf(p, v0.y, o[1]);
            o[2]  = fmaf(p, v0.z, o[2]);  o[3]  = fmaf(p, v0.w, o[3]);
            o[4]  = fmaf(p, v1.x, o[4]);  o[5]  = fmaf(p, v1.y, o[5]);
            o[6]  = fmaf(p, v1.z, o[6]);  o[7]  = fmaf(p, v1.w, o[7]);
            o[8]  = fmaf(p, v2.x, o[8]);  o[9]  = fmaf(p, v2.y, o[9]);
            o[10] = fmaf(p, v2.z, o[10]); o[11] = fmaf(p, v2.w, o[11]);
            o[12] = fmaf(p, v3.x, o[12]); o[13] = fmaf(p, v3.y, o[13]);
            o[14] = fmaf(p, v3.z, o[14]); o[15] = fmaf(p, v3.w, o[15]);
        }
        m = mn;
        __syncthreads();  // protect LDS before next tile's staging
    }

    const float inv = 1.0f / l;
    float* op = out + base + (long)grow * D_HEAD_C + part * 16;
    const float4 o0 = make_float4(o[0] * inv,  o[1] * inv,  o[2] * inv,  o[3] * inv);
    const float4 o1 = make_float4(o[4] * inv,  o[5] * inv,  o[6] * inv,  o[7] * inv);
    const float4 o2 = make_float4(o[8] * inv,  o[9] * inv,  o[10] * inv, o[11] * inv);
    const float4 o3 = make_float4(o[12] * inv, o[13] * inv, o[14] * inv, o[15] * inv);
    *reinterpret_cast<float4*>(op + 0)  = o0;
    *reinterpret_cast<float4*>(op + 4)  = o1;
    *reinterpret_cast<float4*>(op + 8)  = o2;
    *reinterpret_cast<float4*>(op + 12) = o3;
}

extern "C" void kernel_launch(void* const* d_in, const int* in_sizes, int n_in,
                              void* d_out, int out_size, void* d_ws, size_t ws_size,
                              hipStream_t stream) {
    const float* x  = (const float*)d_in[0];
    const float* Wq = (const float*)d_in[1];
    const float* bq = (const float*)d_in[2];
    const float* Wk = (const float*)d_in[3];
    const float* bk = (const float*)d_in[4];
    const float* Wv = (const float*)d_in[5];
    const float* bv = (const float*)d_in[6];
    float* out = (float*)d_out;

    const size_t n = (size_t)B_C * S_C * D_HEAD_C;  // 1,048,576 elems per proj
    float* Q = (float*)d_ws;
    float* K = Q + n;
    float* V = K + n;  // total 12 MiB of ws

    const dim3 pgrid(B_C * S_C / PROWS);  // 2048 blocks
    hipLaunchKernelGGL(qkv_proj_kernel, pgrid, dim3(PTHREADS), 0, stream,
                       x, Wq, bq, Wk, bk, Wv, bv, Q, K, V);

    const dim3 agrid(S_C / QT, B_C);      // (128, 4) = 512 blocks, reversed inside
    hipLaunchKernelGGL(attn_kernel, agrid, dim3(ATHREADS), 0, stream, Q, K, V, out);
}

// Round 3
// 158.538 us; speedup vs baseline: 5.3134x; 5.3134x over previous
//
#include <hip/hip_runtime.h>

typedef __attribute__((ext_vector_type(4))) float f32x4;
typedef __attribute__((ext_vector_type(8))) short short8;
typedef unsigned short ushort_t;

constexpr int DM = 1024, DH = 64, S = 4096, B = 4;
// fold softmax scale 1/sqrt(64) AND log2(e) into Q so scores are in exp2 units
constexpr float QSCALE = 0.125f * 1.44269504088896340736f;

// ws layout (bytes)
constexpr size_t WBT_OFF = 0;                    // Wbt: [192][1024] bf16 (W transposed)
constexpr size_t QB_OFF  = 393216;               // Qb:  [B*S][64] bf16, pre-scaled
constexpr size_t KB_OFF  = QB_OFF + 2097152;     // Kb:  [B*S][64] bf16, chunk-swizzled
constexpr size_t VT_OFF  = KB_OFF + 2097152;     // Vtb: [B][64][S] bf16, chunk-swizzled

__device__ __forceinline__ ushort_t f2bf(float f) {  // RNE f32->bf16
    unsigned u = __float_as_uint(f);
    u += 0x7FFFu + ((u >> 16) & 1u);
    return (ushort_t)(u >> 16);
}

__device__ __forceinline__ void gl_lds16(const void* g, void* l) {
    __builtin_amdgcn_global_load_lds(
        (const __attribute__((address_space(1))) unsigned int*)g,
        (__attribute__((address_space(3))) unsigned int*)l, 16, 0, 0);
}

// ---------------- prep: W fp32 [1024][64] -> Wbt bf16 [192][1024] (transposed) ----
__global__ __launch_bounds__(256) void prep_w_kernel(
    const float* __restrict__ Wq, const float* __restrict__ Wk,
    const float* __restrict__ Wv, ushort_t* __restrict__ wbt)
{
    const int n = blockIdx.x;            // 0..191 : [Q(0-63)|K(64-127)|V(128-191)]
    const int p = n >> 6, d = n & 63;
    const float* W = (p == 0) ? Wq : (p == 1) ? Wk : Wv;
    const int k0 = threadIdx.x * 4;
    ushort4 pack;
    pack.x = f2bf(W[(k0 + 0) * DH + d]);
    pack.y = f2bf(W[(k0 + 1) * DH + d]);
    pack.z = f2bf(W[(k0 + 2) * DH + d]);
    pack.w = f2bf(W[(k0 + 3) * DH + d]);
    *reinterpret_cast<ushort4*>(wbt + (size_t)n * DM + k0) = pack;
}

// ---------------- QKV projection, MFMA, no LDS ----------------
// Block = 128 thr (2 waves); wave owns 32 rows (2 m-tiles of 16); 12 n-tiles = Q|K|V.
// A-frag: 8 contiguous fp32 from x, cvt->bf16 in regs. B-frag: 16B from Wbt (L2-hot).
__global__ __launch_bounds__(128) void qkv_mfma_kernel(
    const float* __restrict__ x, const ushort_t* __restrict__ wbt,
    const float* __restrict__ bq, const float* __restrict__ bk,
    const float* __restrict__ bv,
    ushort_t* __restrict__ qb, ushort_t* __restrict__ kb, ushort_t* __restrict__ vt)
{
    const int tid = threadIdx.x;
    const int wid = tid >> 6, lane = tid & 63;
    const int q16 = lane & 15, lg = lane >> 4;
    const int m0 = blockIdx.x * 64 + wid * 32;

    float bias[12];
#pragma unroll
    for (int nt = 0; nt < 12; ++nt) {
        const int p = nt >> 2, d = ((nt & 3) << 4) + q16;
        const float* bp = (p == 0) ? bq : (p == 1) ? bk : bv;
        bias[nt] = bp[d];
    }

    f32x4 acc[2][12];
#pragma unroll
    for (int mt = 0; mt < 2; ++mt)
#pragma unroll
        for (int nt = 0; nt < 12; ++nt) acc[mt][nt] = {0.f, 0.f, 0.f, 0.f};

    const float* xr0 = x + (size_t)(m0 + q16) * DM;
    const float* xr1 = x + (size_t)(m0 + 16 + q16) * DM;

    for (int kk = 0; kk < DM; kk += 32) {
        const int ko = kk + lg * 8;
        const float4 a0 = *reinterpret_cast<const float4*>(xr0 + ko);
        const float4 a1 = *reinterpret_cast<const float4*>(xr0 + ko + 4);
        const float4 c0 = *reinterpret_cast<const float4*>(xr1 + ko);
        const float4 c1 = *reinterpret_cast<const float4*>(xr1 + ko + 4);
        short8 A0, A1;
        A0[0] = (short)f2bf(a0.x); A0[1] = (short)f2bf(a0.y);
        A0[2] = (short)f2bf(a0.z); A0[3] = (short)f2bf(a0.w);
        A0[4] = (short)f2bf(a1.x); A0[5] = (short)f2bf(a1.y);
        A0[6] = (short)f2bf(a1.z); A0[7] = (short)f2bf(a1.w);
        A1[0] = (short)f2bf(c0.x); A1[1] = (short)f2bf(c0.y);
        A1[2] = (short)f2bf(c0.z); A1[3] = (short)f2bf(c0.w);
        A1[4] = (short)f2bf(c1.x); A1[5] = (short)f2bf(c1.y);
        A1[6] = (short)f2bf(c1.z); A1[7] = (short)f2bf(c1.w);
#pragma unroll
        for (int nt = 0; nt < 12; ++nt) {
            const short8 Bf = *reinterpret_cast<const short8*>(
                wbt + (size_t)(nt * 16 + q16) * DM + ko);
            acc[0][nt] = __builtin_amdgcn_mfma_f32_16x16x32_bf16(A0, Bf, acc[0][nt], 0, 0, 0);
            acc[1][nt] = __builtin_amdgcn_mfma_f32_16x16x32_bf16(A1, Bf, acc[1][nt], 0, 0, 0);
        }
    }

    // Epilogue: C/D layout row=(lane>>4)*4+reg, col=lane&15.
#pragma unroll
    for (int mt = 0; mt < 2; ++mt) {
#pragma unroll
        for (int nt = 0; nt < 12; ++nt) {
            const int p = nt >> 2, d = ((nt & 3) << 4) + q16;
            const float bb = bias[nt];
#pragma unroll
            for (int r = 0; r < 4; ++r) {
                const int m = m0 + mt * 16 + (lg << 2) + r;
                const float v = acc[mt][nt][r] + bb;
                if (p == 0) {
                    qb[(size_t)m * 64 + d] = f2bf(v * QSCALE);
                } else if (p == 1) {
                    // chunk-swizzle: 16B chunk (d>>3) stored at (d>>3)^(m&7)
                    kb[(size_t)m * 64 + (((d >> 3) ^ (m & 7)) << 3) + (d & 7)] = f2bf(v);
                } else {
                    const int bb_ = m >> 12, s = m & 4095;
                    vt[(size_t)bb_ * 262144 + (size_t)d * 4096 + (s & ~63)
                       + ((((s >> 3) & 7) ^ (d & 7)) << 3) + (s & 7)] = f2bf(v);
                }
            }
        }
    }
}

// ---------------- causal flash attention, MFMA ----------------
// Block = 128 thr (2 waves); wave owns 16 q-rows; KV tile 64.
// S^T = mfma(A=K, B=Q) -> lane holds 16 scores of ONE q-column (q = lane&15):
// softmax = in-lane fmax/adds + shfl_xor(16,32). P -> LDS (swizzled) -> A-frag.
// O = mfma(A=P, B=V[as Vt rows]) accumulated over tiles with online rescale.
// NOTE (R2 bugfix): softmax state (m,l,corr) is per q-COLUMN q16, but o[nt][r]
// rows are q = 4*lg + r -> corr must be redistributed via __shfl before rescale.
__global__ __launch_bounds__(128) void attn_mfma_kernel(
    const ushort_t* __restrict__ qb, const ushort_t* __restrict__ kb,
    const ushort_t* __restrict__ vt, float* __restrict__ out)
{
    __shared__ uint4 KsU[512];        // 8 KiB: [64 kv][64 d] bf16 (chunks swizzled)
    __shared__ uint4 VsU[512];        // 8 KiB: [64 d][64 kv] bf16 (chunks swizzled)
    __shared__ uint2 PsU[2][256];     // per-wave 2 KiB: [16 q][64 kv] bf16

    const int tid = threadIdx.x;
    const int wid = tid >> 6, lane = tid & 63;
    const int q16 = lane & 15, lg = lane >> 4;

    // XCD-chunked mapping: xcd = linear&7 (pair of XCDs per batch) so each XCD's
    // L2 holds one batch's K/V (2 MB); idx ascending -> qt descending (heavy first).
    const int linear = blockIdx.x;            // 0..511
    const int xcd = linear & 7, idx = linear >> 3;
    const int b = xcd >> 1;
    const int qt = 127 - (idx * 2 + (xcd & 1));

    const int qrow = qt * 32 + wid * 16 + q16;            // this lane's q (column)
    const char* QbB = (const char*)qb + (size_t)b * S * 128;
    const char* KbB = (const char*)kb + (size_t)b * S * 128;
    const char* VtB = (const char*)vt + (size_t)b * 64 * S * 2;

    short8 qf0 = *reinterpret_cast<const short8*>(QbB + ((size_t)qrow * 64 + lg * 8) * 2);
    short8 qf1 = *reinterpret_cast<const short8*>(QbB + ((size_t)qrow * 64 + 32 + lg * 8) * 2);

    f32x4 o[4];
#pragma unroll
    for (int nt = 0; nt < 4; ++nt) o[nt] = {0.f, 0.f, 0.f, 0.f};
    float m = -1e30f, l = 0.f;

    char* KsC = (char*)KsU;
    char* VsC = (char*)VsU;
    char* PsC = (char*)&PsU[wid][0];

    const int ntiles = (qt * 32 + 31) / 64 + 1;
    for (int kt = 0; kt < ntiles; ++kt) {
        const int kv0 = kt * 64;
        // ---- stage K (linear 8KB) and Vt rows (64 x 128B) via global_load_lds ----
#pragma unroll
        for (int sg = 0; sg < 4; ++sg) {
            const int seg = sg * 2 + wid;   // 0..7, wave-uniform
            gl_lds16(KbB + (size_t)kv0 * 128 + seg * 1024 + lane * 16, KsC + seg * 1024);
            const int vd = seg * 8 + (lane >> 3);
            gl_lds16(VtB + ((size_t)vd * S + kv0) * 2 + (lane & 7) * 16, VsC + seg * 1024);
        }
        __syncthreads();

        // ---- S^T = K . Q^T : D[kv][q], lane has q=q16, kv = kv0+16mt+4lg+r ----
        f32x4 st[4];
#pragma unroll
        for (int mt = 0; mt < 4; ++mt) st[mt] = {0.f, 0.f, 0.f, 0.f};
#pragma unroll
        for (int ks = 0; ks < 2; ++ks) {
#pragma unroll
            for (int mt = 0; mt < 4; ++mt) {
                const short8 kf = *reinterpret_cast<const short8*>(
                    KsC + (mt * 16 + q16) * 128 + (((lg + 4 * ks) ^ (q16 & 7)) << 4));
                st[mt] = __builtin_amdgcn_mfma_f32_16x16x32_bf16(
                    kf, (ks ? qf1 : qf0), st[mt], 0, 0, 0);
            }
        }

        // ---- causal mask (only boundary tiles; wave-uniform branch) ----
        if (kv0 + 63 > qt * 32 + wid * 16) {
#pragma unroll
            for (int mt = 0; mt < 4; ++mt)
#pragma unroll
                for (int r = 0; r < 4; ++r)
                    if (kv0 + mt * 16 + (lg << 2) + r > qrow) st[mt][r] = -1e30f;
        }

        // ---- online softmax (scores already in log2 units), per q-column q16 ----
        float tm = -1e30f;
#pragma unroll
        for (int mt = 0; mt < 4; ++mt)
#pragma unroll
            for (int r = 0; r < 4; ++r) tm = fmaxf(tm, st[mt][r]);
        tm = fmaxf(tm, __shfl_xor(tm, 16));
        tm = fmaxf(tm, __shfl_xor(tm, 32));
        const float mn = fmaxf(m, tm);
        const float corr = exp2f(m - mn);
        float ps = 0.f;
#pragma unroll
        for (int mt = 0; mt < 4; ++mt)
#pragma unroll
            for (int r = 0; r < 4; ++r) {
                const float pv = exp2f(st[mt][r] - mn);
                st[mt][r] = pv;
                ps += pv;
            }
        ps += __shfl_xor(ps, 16);
        ps += __shfl_xor(ps, 32);
        l = l * corr + ps;
        m = mn;

        // ---- R2 BUGFIX: o rows are q = 4lg+r, but corr is for q-col q16.
        // Lane (4lg+r) in [0,16) holds corr for q-column 4lg+r -> shfl it over.
        float corr_row[4];
#pragma unroll
        for (int r = 0; r < 4; ++r) corr_row[r] = __shfl(corr, (lg << 2) | r);
#pragma unroll
        for (int nt = 0; nt < 4; ++nt)
#pragma unroll
            for (int r = 0; r < 4; ++r) o[nt][r] *= corr_row[r];

        // ---- P (bf16) -> LDS, swizzled; readback as PV A-frags ----
#pragma unroll
        for (int mt = 0; mt < 4; ++mt) {
            uint2 w;
            w.x = (unsigned)f2bf(st[mt][0]) | ((unsigned)f2bf(st[mt][1]) << 16);
            w.y = (unsigned)f2bf(st[mt][2]) | ((unsigned)f2bf(st[mt][3]) << 16);
            const int ch = (2 * mt + (lg >> 1)) ^ (q16 & 7);
            *reinterpret_cast<uint2*>(PsC + q16 * 128 + ch * 16 + (lg & 1) * 8) = w;
        }
        const short8 pa0 = *reinterpret_cast<const short8*>(
            PsC + q16 * 128 + ((lg ^ (q16 & 7)) << 4));
        const short8 pa1 = *reinterpret_cast<const short8*>(
            PsC + q16 * 128 + (((lg + 4) ^ (q16 & 7)) << 4));

        // ---- O += P . V : D[q][d], row=4lg+r, col=16nt+q16 ----
#pragma unroll
        for (int ks = 0; ks < 2; ++ks) {
#pragma unroll
            for (int nt = 0; nt < 4; ++nt) {
                const short8 vf = *reinterpret_cast<const short8*>(
                    VsC + (nt * 16 + q16) * 128 + (((lg + 4 * ks) ^ (q16 & 7)) << 4));
                o[nt] = __builtin_amdgcn_mfma_f32_16x16x32_bf16(
                    (ks ? pa1 : pa0), vf, o[nt], 0, 0, 0);
            }
        }
        __syncthreads();
    }

    // ---- epilogue: redistribute l (lane has l for q=q16; o rows are 4lg+r) ----
    float linv[4];
#pragma unroll
    for (int r = 0; r < 4; ++r) linv[r] = 1.0f / __shfl(l, (lg << 2) | r);
    float* ob = out + (size_t)b * S * DH;
#pragma unroll
    for (int nt = 0; nt < 4; ++nt)
#pragma unroll
        for (int r = 0; r < 4; ++r)
            ob[(size_t)(qt * 32 + wid * 16 + (lg << 2) + r) * 64 + nt * 16 + q16] =
                o[nt][r] * linv[r];
}

extern "C" void kernel_launch(void* const* d_in, const int* in_sizes, int n_in,
                              void* d_out, int out_size, void* d_ws, size_t ws_size,
                              hipStream_t stream) {
    const float* x  = (const float*)d_in[0];
    const float* Wq = (const float*)d_in[1];
    const float* bq = (const float*)d_in[2];
    const float* Wk = (const float*)d_in[3];
    const float* bk = (const float*)d_in[4];
    const float* Wv = (const float*)d_in[5];
    const float* bv = (const float*)d_in[6];
    float* out = (float*)d_out;

    char* ws = (char*)d_ws;
    ushort_t* wbt = (ushort_t*)(ws + WBT_OFF);
    ushort_t* qbp = (ushort_t*)(ws + QB_OFF);
    ushort_t* kbp = (ushort_t*)(ws + KB_OFF);
    ushort_t* vtp = (ushort_t*)(ws + VT_OFF);

    hipLaunchKernelGGL(prep_w_kernel, dim3(192), dim3(256), 0, stream, Wq, Wk, Wv, wbt);
    hipLaunchKernelGGL(qkv_mfma_kernel, dim3(256), dim3(128), 0, stream,
                       x, wbt, bq, bk, bv, qbp, kbp, vtp);
    hipLaunchKernelGGL(attn_mfma_kernel, dim3(512), dim3(128), 0, stream,
                       qbp, kbp, vtp, out);
}

// Round 4
// 116.496 us; speedup vs baseline: 7.2309x; 1.3609x over previous
//
#include <hip/hip_runtime.h>

typedef __attribute__((ext_vector_type(4))) float f32x4;
typedef __attribute__((ext_vector_type(8))) short short8;
typedef unsigned short ushort_t;

constexpr int DM = 1024, DH = 64, S = 4096, B = 4;
// fold softmax scale 1/sqrt(64) AND log2(e) into Q so scores are in exp2 units
constexpr float QSCALE = 0.125f * 1.44269504088896340736f;

// ws layout (bytes)
constexpr size_t WBT_OFF = 0;                    // Wbt: [192][1024] bf16 (W transposed)
constexpr size_t QB_OFF  = 393216;               // Qb:  [B*S][64] bf16, pre-scaled
constexpr size_t KB_OFF  = QB_OFF + 2097152;     // Kb:  [B*S][64] bf16, chunk-swizzled
constexpr size_t VT_OFF  = KB_OFF + 2097152;     // Vtb: [B][64][S] bf16, chunk-swizzled

__device__ __forceinline__ ushort_t f2bf(float f) {  // RNE f32->bf16
    unsigned u = __float_as_uint(f);
    u += 0x7FFFu + ((u >> 16) & 1u);
    return (ushort_t)(u >> 16);
}

__device__ __forceinline__ void gl_lds16(const void* g, void* l) {
    __builtin_amdgcn_global_load_lds(
        (const __attribute__((address_space(1))) unsigned int*)g,
        (__attribute__((address_space(3))) unsigned int*)l, 16, 0, 0);
}

// ---------------- prep: W fp32 [1024][64] -> Wbt bf16 [192][1024] (transposed) ----
__global__ __launch_bounds__(256) void prep_w_kernel(
    const float* __restrict__ Wq, const float* __restrict__ Wk,
    const float* __restrict__ Wv, ushort_t* __restrict__ wbt)
{
    const int n = blockIdx.x;            // 0..191 : [Q(0-63)|K(64-127)|V(128-191)]
    const int p = n >> 6, d = n & 63;
    const float* W = (p == 0) ? Wq : (p == 1) ? Wk : Wv;
    const int k0 = threadIdx.x * 4;
    ushort4 pack;
    pack.x = f2bf(W[(k0 + 0) * DH + d]);
    pack.y = f2bf(W[(k0 + 1) * DH + d]);
    pack.z = f2bf(W[(k0 + 2) * DH + d]);
    pack.w = f2bf(W[(k0 + 3) * DH + d]);
    *reinterpret_cast<ushort4*>(wbt + (size_t)n * DM + k0) = pack;
}

// ---------------- QKV projection, MFMA, k-split x2 ----------------
// Block = 256 thr (4 waves) covering 32 rows: wave = (sub = m-subtile of 16 rows,
// kh = k-half of 512). 2048 waves total -> 2 waves/SIMD. kh=1 waves dump partial
// acc to LDS; kh=0 waves add + epilogue. A-frags cvt'd inline from fp32 x.
__global__ __launch_bounds__(256) void qkv_mfma_kernel(
    const float* __restrict__ x, const ushort_t* __restrict__ wbt,
    const float* __restrict__ bq, const float* __restrict__ bk,
    const float* __restrict__ bv,
    ushort_t* __restrict__ qb, ushort_t* __restrict__ kb, ushort_t* __restrict__ vt)
{
    __shared__ float redF[2][48][64];   // 24 KiB: [sub][nt*4+r][lane], lane-minor

    const int tid = threadIdx.x;
    const int wid = tid >> 6, lane = tid & 63;
    const int q16 = lane & 15, lg = lane >> 4;
    const int sub = wid & 1, kh = wid >> 1;
    const int m0 = blockIdx.x * 32 + sub * 16;

    f32x4 acc[12];
#pragma unroll
    for (int nt = 0; nt < 12; ++nt) acc[nt] = {0.f, 0.f, 0.f, 0.f};

    const float* xr = x + (size_t)(m0 + q16) * DM;
    const int kbase = kh * 512;

    for (int kk = 0; kk < 512; kk += 32) {
        const int ko = kbase + kk + lg * 8;
        const float4 a0 = *reinterpret_cast<const float4*>(xr + ko);
        const float4 a1 = *reinterpret_cast<const float4*>(xr + ko + 4);
        short8 A;
        A[0] = (short)f2bf(a0.x); A[1] = (short)f2bf(a0.y);
        A[2] = (short)f2bf(a0.z); A[3] = (short)f2bf(a0.w);
        A[4] = (short)f2bf(a1.x); A[5] = (short)f2bf(a1.y);
        A[6] = (short)f2bf(a1.z); A[7] = (short)f2bf(a1.w);
#pragma unroll
        for (int nt = 0; nt < 12; ++nt) {
            const short8 Bf = *reinterpret_cast<const short8*>(
                wbt + (size_t)(nt * 16 + q16) * DM + ko);
            acc[nt] = __builtin_amdgcn_mfma_f32_16x16x32_bf16(A, Bf, acc[nt], 0, 0, 0);
        }
    }

    if (kh == 1) {
#pragma unroll
        for (int nt = 0; nt < 12; ++nt)
#pragma unroll
            for (int r = 0; r < 4; ++r)
                redF[sub][nt * 4 + r][lane] = acc[nt][r];
    }
    __syncthreads();
    if (kh == 0) {
#pragma unroll
        for (int nt = 0; nt < 12; ++nt)
#pragma unroll
            for (int r = 0; r < 4; ++r)
                acc[nt][r] += redF[sub][nt * 4 + r][lane];

        // Epilogue: C/D layout row=(lane>>4)*4+reg, col=lane&15.
#pragma unroll
        for (int nt = 0; nt < 12; ++nt) {
            const int p = nt >> 2, d = ((nt & 3) << 4) + q16;
            const float* bp = (p == 0) ? bq : (p == 1) ? bk : bv;
            const float bb = bp[d];
#pragma unroll
            for (int r = 0; r < 4; ++r) {
                const int m = m0 + (lg << 2) + r;
                const float v = acc[nt][r] + bb;
                if (p == 0) {
                    qb[(size_t)m * 64 + d] = f2bf(v * QSCALE);
                } else if (p == 1) {
                    // chunk-swizzle: 16B chunk (d>>3) stored at (d>>3)^(m&7)
                    kb[(size_t)m * 64 + (((d >> 3) ^ (m & 7)) << 3) + (d & 7)] = f2bf(v);
                } else {
                    const int bb_ = m >> 12, s = m & 4095;
                    vt[(size_t)bb_ * 262144 + (size_t)d * 4096 + (s & ~63)
                       + ((((s >> 3) & 7) ^ (d & 7)) << 3) + (s & 7)] = f2bf(v);
                }
            }
        }
    }
}

// ---------------- causal flash attention, MFMA, split-KV x2 + prefetch ----------------
// Block = 256 thr (4 waves) on 32 q-rows. grp = wid>>1 processes even (0) / odd (1)
// KV tiles with its own double-buffered K/V LDS; sub = wid&1 picks the 16-row half.
// Prefetch: issue next tile's global_load_lds BEFORE computing current tile.
// End: merge the two groups' (m,l,o) via LDS (P buffers reused as merge space).
__global__ __launch_bounds__(256) void attn_mfma_kernel(
    const ushort_t* __restrict__ qb, const ushort_t* __restrict__ kb,
    const ushort_t* __restrict__ vt, float* __restrict__ out)
{
    __shared__ char Ls[2][2][16384];   // 64 KiB: [grp][buf][K 8KB | V 8KB], swizzled chunks
    __shared__ uint2 PsU[4][256];      // 8 KiB per-wave P; reused as merge o-buffer
    __shared__ float MLs[2][2][16];    // [sub][{m,l}][q16]

    const int tid = threadIdx.x;
    const int wid = tid >> 6, lane = tid & 63;
    const int q16 = lane & 15, lg = lane >> 4;
    const int sub = wid & 1, grp = wid >> 1;

    // XCD-chunked mapping; idx ascending -> qt descending (heavy diagonal first).
    const int linear = blockIdx.x;            // 0..511
    const int xcd = linear & 7, idx = linear >> 3;
    const int b = xcd >> 1;
    const int qt = 127 - (idx * 2 + (xcd & 1));

    const int qrow = qt * 32 + sub * 16 + q16;            // this lane's q (column)
    const char* QbB = (const char*)qb + (size_t)b * S * 128;
    const char* KbB = (const char*)kb + (size_t)b * S * 128;
    const char* VtB = (const char*)vt + (size_t)b * 64 * S * 2;

    const short8 qf0 = *reinterpret_cast<const short8*>(QbB + ((size_t)qrow * 64 + lg * 8) * 2);
    const short8 qf1 = *reinterpret_cast<const short8*>(QbB + ((size_t)qrow * 64 + 32 + lg * 8) * 2);

    f32x4 o[4];
#pragma unroll
    for (int nt = 0; nt < 4; ++nt) o[nt] = {0.f, 0.f, 0.f, 0.f};
    float m = -1e30f, l = 0.f;

    char* PsC = (char*)&PsU[wid][0];

    const int ntiles = (qt * 32 + 31) / 64 + 1;
    const int niter  = (ntiles + 1) >> 1;

    auto stage = [&](int t, int buf) {
        char* KsC = &Ls[grp][buf][0];
        char* VsC = KsC + 8192;
        const int kv0 = t * 64;
#pragma unroll
        for (int sg = 0; sg < 4; ++sg) {
            const int seg = sg * 2 + sub;   // 0..7, wave-uniform
            gl_lds16(KbB + (size_t)kv0 * 128 + seg * 1024 + lane * 16, KsC + seg * 1024);
            const int vd = seg * 8 + (lane >> 3);
            gl_lds16(VtB + ((size_t)vd * S + kv0) * 2 + (lane & 7) * 16, VsC + seg * 1024);
        }
    };

    // prologue: both groups stage their first tile into buf 0
    if (grp < ntiles) stage(grp, 0);
    __syncthreads();

    int cur = 0;
    for (int i = 0; i < niter; ++i) {
        const int t = 2 * i + grp;
        const int tn = t + 2;
        if (tn < ntiles) stage(tn, cur ^ 1);   // prefetch overlaps compute below

        if (t < ntiles) {
            char* KsC = &Ls[grp][cur][0];
            char* VsC = KsC + 8192;
            const int kv0 = t * 64;

            // ---- S^T = K . Q^T : D[kv][q], lane has q=q16, kv = kv0+16mt+4lg+r ----
            f32x4 st[4];
#pragma unroll
            for (int mt = 0; mt < 4; ++mt) st[mt] = {0.f, 0.f, 0.f, 0.f};
            __builtin_amdgcn_s_setprio(1);
#pragma unroll
            for (int ks = 0; ks < 2; ++ks) {
#pragma unroll
                for (int mt = 0; mt < 4; ++mt) {
                    const short8 kf = *reinterpret_cast<const short8*>(
                        KsC + (mt * 16 + q16) * 128 + (((lg + 4 * ks) ^ (q16 & 7)) << 4));
                    st[mt] = __builtin_amdgcn_mfma_f32_16x16x32_bf16(
                        kf, (ks ? qf1 : qf0), st[mt], 0, 0, 0);
                }
            }
            __builtin_amdgcn_s_setprio(0);

            // ---- causal mask (boundary tiles only; wave-uniform branch) ----
            if (kv0 + 63 > qt * 32 + sub * 16) {
#pragma unroll
                for (int mt = 0; mt < 4; ++mt)
#pragma unroll
                    for (int r = 0; r < 4; ++r)
                        if (kv0 + mt * 16 + (lg << 2) + r > qrow) st[mt][r] = -1e30f;
            }

            // ---- online softmax (log2 units), per q-column q16 ----
            float tm = -1e30f;
#pragma unroll
            for (int mt = 0; mt < 4; ++mt)
#pragma unroll
                for (int r = 0; r < 4; ++r) tm = fmaxf(tm, st[mt][r]);
            tm = fmaxf(tm, __shfl_xor(tm, 16));
            tm = fmaxf(tm, __shfl_xor(tm, 32));
            const float mn = fmaxf(m, tm);
            const float corr = exp2f(m - mn);
            float ps = 0.f;
#pragma unroll
            for (int mt = 0; mt < 4; ++mt)
#pragma unroll
                for (int r = 0; r < 4; ++r) {
                    const float pv = exp2f(st[mt][r] - mn);
                    st[mt][r] = pv;
                    ps += pv;
                }
            ps += __shfl_xor(ps, 16);
            ps += __shfl_xor(ps, 32);
            l = l * corr + ps;
            m = mn;

            // o rows are q = 4lg+r but corr is per q-col q16 -> redistribute.
            float corr_row[4];
#pragma unroll
            for (int r = 0; r < 4; ++r) corr_row[r] = __shfl(corr, (lg << 2) | r);
#pragma unroll
            for (int nt = 0; nt < 4; ++nt)
#pragma unroll
                for (int r = 0; r < 4; ++r) o[nt][r] *= corr_row[r];

            // ---- P (bf16) -> per-wave LDS, swizzled; readback as PV A-frags ----
#pragma unroll
            for (int mt = 0; mt < 4; ++mt) {
                uint2 w;
                w.x = (unsigned)f2bf(st[mt][0]) | ((unsigned)f2bf(st[mt][1]) << 16);
                w.y = (unsigned)f2bf(st[mt][2]) | ((unsigned)f2bf(st[mt][3]) << 16);
                const int ch = (2 * mt + (lg >> 1)) ^ (q16 & 7);
                *reinterpret_cast<uint2*>(PsC + q16 * 128 + ch * 16 + (lg & 1) * 8) = w;
            }
            const short8 pa0 = *reinterpret_cast<const short8*>(
                PsC + q16 * 128 + ((lg ^ (q16 & 7)) << 4));
            const short8 pa1 = *reinterpret_cast<const short8*>(
                PsC + q16 * 128 + (((lg + 4) ^ (q16 & 7)) << 4));

            // ---- O += P . V : D[q][d], row=4lg+r, col=16nt+q16 ----
            __builtin_amdgcn_s_setprio(1);
#pragma unroll
            for (int ks = 0; ks < 2; ++ks) {
#pragma unroll
                for (int nt = 0; nt < 4; ++nt) {
                    const short8 vf = *reinterpret_cast<const short8*>(
                        VsC + (nt * 16 + q16) * 128 + (((lg + 4 * ks) ^ (q16 & 7)) << 4));
                    o[nt] = __builtin_amdgcn_mfma_f32_16x16x32_bf16(
                        (ks ? pa1 : pa0), vf, o[nt], 0, 0, 0);
                }
            }
            __builtin_amdgcn_s_setprio(0);
        }
        __syncthreads();
        cur ^= 1;
    }

    // ---- merge group 1 into group 0 (P buffers dead -> reuse as merge space) ----
    float* mergeF = (float*)PsU;   // [sub][16 w][64 lane] floats, lane-minor
    if (grp == 1) {
#pragma unroll
        for (int nt = 0; nt < 4; ++nt)
#pragma unroll
            for (int r = 0; r < 4; ++r)
                mergeF[sub * 1024 + (nt * 4 + r) * 64 + lane] = o[nt][r];
        if (lg == 0) { MLs[sub][0][q16] = m; MLs[sub][1][q16] = l; }
    }
    __syncthreads();
    if (grp == 0) {
        const float m2 = MLs[sub][0][q16], l2 = MLs[sub][1][q16];
        const float mm = fmaxf(m, m2);
        const float c1 = exp2f(m - mm), c2 = exp2f(m2 - mm);
        const float linvq = 1.0f / (l * c1 + l2 * c2);
        const float a1 = c1 * linvq, a2 = c2 * linvq;
        float a1r[4], a2r[4];
#pragma unroll
        for (int r = 0; r < 4; ++r) {
            a1r[r] = __shfl(a1, (lg << 2) | r);
            a2r[r] = __shfl(a2, (lg << 2) | r);
        }
        float* ob = out + (size_t)b * S * DH;
#pragma unroll
        for (int nt = 0; nt < 4; ++nt)
#pragma unroll
            for (int r = 0; r < 4; ++r) {
                const float o2 = mergeF[sub * 1024 + (nt * 4 + r) * 64 + lane];
                ob[(size_t)(qt * 32 + sub * 16 + (lg << 2) + r) * 64 + nt * 16 + q16] =
                    o[nt][r] * a1r[r] + o2 * a2r[r];
            }
    }
}

extern "C" void kernel_launch(void* const* d_in, const int* in_sizes, int n_in,
                              void* d_out, int out_size, void* d_ws, size_t ws_size,
                              hipStream_t stream) {
    const float* x  = (const float*)d_in[0];
    const float* Wq = (const float*)d_in[1];
    const float* bq = (const float*)d_in[2];
    const float* Wk = (const float*)d_in[3];
    const float* bk = (const float*)d_in[4];
    const float* Wv = (const float*)d_in[5];
    const float* bv = (const float*)d_in[6];
    float* out = (float*)d_out;

    char* ws = (char*)d_ws;
    ushort_t* wbt = (ushort_t*)(ws + WBT_OFF);
    ushort_t* qbp = (ushort_t*)(ws + QB_OFF);
    ushort_t* kbp = (ushort_t*)(ws + KB_OFF);
    ushort_t* vtp = (ushort_t*)(ws + VT_OFF);

    hipLaunchKernelGGL(prep_w_kernel, dim3(192), dim3(256), 0, stream, Wq, Wk, Wv, wbt);
    hipLaunchKernelGGL(qkv_mfma_kernel, dim3(512), dim3(256), 0, stream,
                       x, wbt, bq, bk, bv, qbp, kbp, vtp);
    hipLaunchKernelGGL(attn_mfma_kernel, dim3(512), dim3(256), 0, stream,
                       qbp, kbp, vtp, out);
}